// Round 16
// baseline (268.605 us; speedup 1.0000x reference)
//
#include <hip/hip_runtime.h>
#include <stdint.h>

#define BTOK 2048
#define HDIM 512
#define VOC  32000
#define BM 128
#define BN 128
#define BKM 64                   // K per step (MX 32x32x64)
#define NKTM (HDIM / BKM)        // 8 K-steps per vocab block
#define BLOBM (BM * BKM)         // 8192 B per (panel, kt) blob (fp8)
#define NVB (VOC / BN)           // 250
#define NRB (BTOK / BM)          // 16
#define NBLK (NVB * NRB)         // 4000 (fallback grid)
#define VBG 2                    // vocab blocks per strip
#define NVBG (NVB / VBG)         // 125
#define NSTRIP (NVBG * NRB)      // 2000 (% 8 == 0; 1 blk/CU tail waste ~2.5%)
#define NSLOT (NVBG * 2)         // 250 partial slots
#define NSTEP (VBG * NKTM)       // 16 global K-steps per block

// ws layout:
//   [0, 256)        blocksums
//   [65536, ..)     fp8 blobs: s_in | t_in | s_w | t_w
//   [PART_OFF, ..)  partials[5][NSLOT][BTOK] f32
#define WS_BLOB_OFF 65536
#define INB_B ((size_t)BTOK * HDIM)
#define WB_B  ((size_t)VOC * HDIM)
#define BLOB_BYTES (2 * INB_B + 2 * WB_B)          // 34,865,152
#define PART_OFF (WS_BLOB_OFF + BLOB_BYTES)
#define PART_BYTES ((size_t)5 * NSLOT * BTOK * 4)  // 10,240,000
#define WS_NEED (PART_OFF + PART_BYTES)            // ~45.2 MB

typedef __attribute__((ext_vector_type(8)))  short bf16x8;
typedef __attribute__((ext_vector_type(4)))  float f32x4;
typedef __attribute__((ext_vector_type(16))) float f32x16;
typedef __attribute__((ext_vector_type(8)))  int   i32x8;

__device__ __forceinline__ unsigned short f2b(float f) {
    union { float f; uint32_t u; } x; x.f = f;
    uint32_t u = x.u;
    u += 0x7fffu + ((u >> 16) & 1u);   // RNE (fallback path)
    return (unsigned short)(u >> 16);
}

// ---------------------------------------------------------------------------
// Pass 1: f32 -> fp8 e4m3 blobs. R15 piece-interleaved panel layout
// (HW-verified conflict-free: R15 measured SQ_LDS_BANK_CONFLICT = 0):
//   e = (r>>5)*2048 + ((c&31)>>4)*1024 + ((c>>5)*32 + (r&31))*16 + (c&15)
// Lane l's 32B MFMA operand = two 16B pieces at opBase + l*16 / +1024.
// ---------------------------------------------------------------------------
__global__ __launch_bounds__(256) void convert_pack_mx(
    const float* __restrict__ s_in, const float* __restrict__ s_w,
    const float* __restrict__ t_in, const float* __restrict__ t_w,
    unsigned char* __restrict__ blob)
{
    unsigned char* sinb = blob;
    unsigned char* tinb = blob + INB_B;
    unsigned char* swb  = blob + 2 * INB_B;
    unsigned char* twb  = blob + 2 * INB_B + WB_B;
    const int total8 = (2 * BTOK + 2 * VOC) * (HDIM / 8);
    for (int f = blockIdx.x * 256 + threadIdx.x; f < total8; f += gridDim.x * 256) {
        const int row = f >> 6;
        const int c8i = f & 63;
        const float* src; unsigned char* dstb; int lrow;
        if (row < BTOK)                { src = s_in; dstb = sinb; lrow = row; }
        else if (row < BTOK + VOC)     { src = s_w;  dstb = swb;  lrow = row - BTOK; }
        else if (row < 2*BTOK + VOC)   { src = t_in; dstb = tinb; lrow = row - (BTOK + VOC); }
        else                           { src = t_w;  dstb = twb;  lrow = row - (2*BTOK + VOC); }
        const float* sp = src + (size_t)lrow * HDIM + c8i * 8;
        const float4 v0 = *reinterpret_cast<const float4*>(sp);
        const float4 v1 = *reinterpret_cast<const float4*>(sp + 4);
        const int p = lrow >> 7, r = lrow & 127;
        const int ccf = c8i * 8, kt = ccf >> 6, cc = ccf & 63;
        const int e = ((r >> 5) << 11) + (((cc & 31) >> 4) << 10)
                    + ((((cc >> 5) << 5) + (r & 31)) << 4) + (cc & 15);
        uint32_t w0 = 0, w1 = 0;
        w0 = __builtin_amdgcn_cvt_pk_fp8_f32(v0.x, v0.y, w0, false);
        w0 = __builtin_amdgcn_cvt_pk_fp8_f32(v0.z, v0.w, w0, true);
        w1 = __builtin_amdgcn_cvt_pk_fp8_f32(v1.x, v1.y, w1, false);
        w1 = __builtin_amdgcn_cvt_pk_fp8_f32(v1.z, v1.w, w1, true);
        uint2 pk; pk.x = w0; pk.y = w1;
        *reinterpret_cast<uint2*>(dstb + (size_t)(p * NKTM + kt) * BLOBM + e) = pk;
    }
}

__device__ __forceinline__ void gl_lds16(const unsigned char* g, unsigned char* l) {
    __builtin_amdgcn_global_load_lds(
        (__attribute__((address_space(1))) const void*)g,
        (__attribute__((address_space(3))) void*)l, 16, 0, 0);
}

// Read one 32B MFMA operand: two 16B pieces at p and p+1024 (conflict-free).
__device__ __forceinline__ i32x8 ld32pc(const unsigned char* p) {
    const int4 lo = *reinterpret_cast<const int4*>(p);
    const int4 hi = *reinterpret_cast<const int4*>(p + 1024);
    i32x8 v;
    v[0] = lo.x; v[1] = lo.y; v[2] = lo.z; v[3] = lo.w;
    v[4] = hi.x; v[5] = hi.y; v[6] = hi.z; v[7] = hi.w;
    return v;
}

// Stage panels for one step into ring slot SLOT: A(KA) (mod-8 per-rb set),
// B at byte offset KBOFF from the per-g B base (linear across g boundaries:
// consecutive vb panels are contiguous in the blob).
#define STAGE4(SLOT, KA, KBOFF)                                               \
    {                                                                         \
        const int off = tid * 16;                                             \
        gl_lds16(g0 + (size_t)(KA) * BLOBM + off, &smem[SLOT][0][off]);       \
        gl_lds16(pbS + (size_t)(KBOFF) + off, &smem[SLOT][1][off]);           \
        gl_lds16(g2 + (size_t)(KA) * BLOBM + off, &smem[SLOT][2][off]);       \
        gl_lds16(pbT + (size_t)(KBOFF) + off, &smem[SLOT][3][off]);           \
    }

// Per wave: 1 A-frag + 2 B-frags per matrix, 4 mfma_scale (scale=1.0: E8M0 127).
#define COMPUTE_MX(P)                                                         \
    {                                                                         \
        i32x8 fa, fb0, fb1;                                                   \
        fa  = ld32pc(&smem[P][0][aOff]);                                      \
        fb0 = ld32pc(&smem[P][1][b0Off]);                                     \
        fb1 = ld32pc(&smem[P][1][b1Off]);                                     \
        acc_s0 = __builtin_amdgcn_mfma_scale_f32_32x32x64_f8f6f4(             \
            fa, fb0, acc_s0, 0, 0, 0, 127, 0, 127);                           \
        acc_s1 = __builtin_amdgcn_mfma_scale_f32_32x32x64_f8f6f4(             \
            fa, fb1, acc_s1, 0, 0, 0, 127, 0, 127);                           \
        fa  = ld32pc(&smem[P][2][aOff]);                                      \
        fb0 = ld32pc(&smem[P][3][b0Off]);                                     \
        fb1 = ld32pc(&smem[P][3][b1Off]);                                     \
        acc_t0 = __builtin_amdgcn_mfma_scale_f32_32x32x64_f8f6f4(             \
            fa, fb0, acc_t0, 0, 0, 0, 127, 0, 127);                           \
        acc_t1 = __builtin_amdgcn_mfma_scale_f32_32x32x64_f8f6f4(             \
            fa, fb1, acc_t1, 0, 0, 0, 127, 0, 127);                          \
    }

#define VM_WAIT(N) asm volatile("s_waitcnt vmcnt(" #N ")" ::: "memory")

// ---------------------------------------------------------------------------
// Strip GEMM (MX fp8 32x32x64, 8 waves, VBG=2). Ring-4 LDS (128 KB, 1
// block/CU), 2-deep prefetch, ONE barrier/step. Ring slot = kt&3 is STATIC
// (8 steps/g == 0 mod 4, g-loop runtime -- the no-spill recipe). vmcnt:
// steady 8 outstanding at step entry {stage(s), stage(s+1)}; +4 staged ->
// vmcnt(8) drains exactly stage(s). Tail: vmcnt(4), vmcnt(0). WAR: step s
// writes slot (s+2)&3 = slot last read at s-2; those lgkmcnt-completed
// before their wave reached barrier(s-1), which precedes our stage issue.
// ---------------------------------------------------------------------------
__global__ __launch_bounds__(512, 2) void fused_gemm_mx(
    const unsigned char* __restrict__ blob,
    const int* __restrict__ labels, float* __restrict__ partials)
{
    __shared__ __align__(16) unsigned char smem[4][4][BLOBM];   // 128 KB ring
    __shared__ int lbl[BM];
    const unsigned char* sinb = blob;
    const unsigned char* tinb = blob + INB_B;
    const unsigned char* swb  = blob + 2 * INB_B;
    const unsigned char* twb  = blob + 2 * INB_B + WB_B;

    const int tid = threadIdx.x;
    const int orig = blockIdx.x;
    const int swzb = (orig & 7) * (NSTRIP / 8) + (orig >> 3);   // XCD-bijective
    const int vbg = swzb >> 4, rb = swzb & 15;
    const int row0 = rb * BM;
    if (tid < BM) lbl[tid] = labels[row0 + tid];
    __syncthreads();

    const int lane = tid & 63, wave = tid >> 6;
    const int wm = (wave >> 1) * 32;      // 4 M-strips of 32
    const int wn = (wave & 1) * 64;       // 2 N-strips of 64
    const int lrow = lane & 31, khalf = lane >> 5;

    // piece-layout fragment offsets: strip*2048 + lane*16 (piece1 at +1024)
    const int aOff  = ((wm >> 5) << 11) + lane * 16;
    const int b0Off = ((wn >> 5) << 11) + lane * 16;
    const int b1Off = b0Off + 2048;

    const unsigned char* g0 = sinb + (size_t)(rb * NKTM) * BLOBM;
    const unsigned char* g2 = tinb + (size_t)(rb * NKTM) * BLOBM;
    const unsigned char* pbS = swb + (size_t)(vbg * VBG * NKTM) * BLOBM;
    const unsigned char* pbT = twb + (size_t)(vbg * VBG * NKTM) * BLOBM;

    // labels for this thread's 16 output rows
    int labr[16];
#pragma unroll
    for (int rg = 0; rg < 16; ++rg)
        labr[rg] = lbl[wm + (rg & 3) + 8 * (rg >> 2) + 4 * khalf];

    // strip-accumulated loss partials (statically indexed)
    float pes[16], pdt[16], pss[16], ptt[16], psl[16];
#pragma unroll
    for (int i = 0; i < 16; ++i) {
        pes[i] = 0.f; pdt[i] = 0.f; pss[i] = 0.f; ptt[i] = 0.f; psl[i] = 0.f;
    }

    // prologue: stages for steps 0 and 1 (8 loads in flight)
    STAGE4(0, 0, 0);
    STAGE4(1, 1, BLOBM);

    for (int g = 0; g < VBG; ++g) {
        const int n0 = (vbg * VBG + g) * BN;
        f32x16 acc_s0 = {}, acc_s1 = {}, acc_t0 = {}, acc_t1 = {};

        if (g < VBG - 1) {
#pragma unroll
            for (int kt = 0; kt < NKTM; ++kt) {
                STAGE4((kt + 2) & 3, (kt + 2) & 7, (size_t)(kt + 2) * BLOBM);
                VM_WAIT(8);
                __builtin_amdgcn_sched_barrier(0);
                __builtin_amdgcn_s_barrier();
                __builtin_amdgcn_s_setprio(1);
                COMPUTE_MX(kt & 3);
                __builtin_amdgcn_s_setprio(0);
            }
        } else {
#pragma unroll
            for (int kt = 0; kt < NKTM; ++kt) {
                if (kt < NKTM - 2) {
                    STAGE4((kt + 2) & 3, (kt + 2) & 7, (size_t)(kt + 2) * BLOBM);
                    VM_WAIT(8);
                } else if (kt == NKTM - 2) {
                    VM_WAIT(4);
                } else {
                    VM_WAIT(0);
                }
                __builtin_amdgcn_sched_barrier(0);
                __builtin_amdgcn_s_barrier();
                __builtin_amdgcn_s_setprio(1);
                COMPUTE_MX(kt & 3);
                __builtin_amdgcn_s_setprio(0);
            }
        }
        pbS += (size_t)NKTM * BLOBM;
        pbT += (size_t)NKTM * BLOBM;

        // accumulate into register partials
        // C/D (32x32): col = lane&31, row = (reg&3)+8*(reg>>2)+4*(lane>>5)
#pragma unroll
        for (int rg = 0; rg < 16; ++rg) {
            const float s0 = acc_s0[rg], s1 = acc_s1[rg];
            const float t0 = acc_t0[rg], t1 = acc_t1[rg];
            pes[rg] += __expf(s0) + __expf(s1);
            pdt[rg] += s0 * t0 + s1 * t1;
            pss[rg] += s0 * s0 + s1 * s1;
            ptt[rg] += t0 * t0 + t1 * t1;
            const int lab = labr[rg];
            if (n0 + wn + lrow == lab)      psl[rg] += s0;
            if (n0 + wn + 32 + lrow == lab) psl[rg] += s1;
        }
    }

    // one shuffle-reduce + one non-atomic write per rg for the whole strip
    const int slot = vbg * 2 + (wave & 1);
#pragma unroll
    for (int rg = 0; rg < 16; ++rg) {
        float es = pes[rg], dt = pdt[rg], ss = pss[rg], tt = ptt[rg], sl = psl[rg];
#pragma unroll
        for (int m = 1; m < 32; m <<= 1) {
            es += __shfl_xor(es, m, 64);
            dt += __shfl_xor(dt, m, 64);
            ss += __shfl_xor(ss, m, 64);
            tt += __shfl_xor(tt, m, 64);
            sl += __shfl_xor(sl, m, 64);
        }
        if (lrow == 0) {
            const int row = row0 + wm + (rg & 3) + 8 * (rg >> 2) + 4 * khalf;
            partials[(size_t)(0 * NSLOT + slot) * BTOK + row] = es;
            partials[(size_t)(1 * NSLOT + slot) * BTOK + row] = dt;
            partials[(size_t)(2 * NSLOT + slot) * BTOK + row] = ss;
            partials[(size_t)(3 * NSLOT + slot) * BTOK + row] = tt;
            partials[(size_t)(4 * NSLOT + slot) * BTOK + row] = sl;
        }
    }
}

// ---------------------------------------------------------------------------
// finalize stage 1: 32 blocks x 64 rows; reduce 250 slots (coalesced).
// ---------------------------------------------------------------------------
__global__ __launch_bounds__(256) void finalize_s1(
    const float* __restrict__ partials, const int* __restrict__ labels,
    float* __restrict__ blocksums)
{
    __shared__ float fsum[4][64][5];
    const int t = threadIdx.x, b = blockIdx.x;
    const int rl = t & 63, w = t >> 6;
    const int row = b * 64 + rl;
    float a0 = 0.f, a1 = 0.f, a2 = 0.f, a3 = 0.f, a4 = 0.f;
    for (int slot = w; slot < NSLOT; slot += 4) {
        const size_t base = (size_t)slot * BTOK + row;
        a0 += partials[(size_t)0 * NSLOT * BTOK + base];
        a1 += partials[(size_t)1 * NSLOT * BTOK + base];
        a2 += partials[(size_t)2 * NSLOT * BTOK + base];
        a3 += partials[(size_t)3 * NSLOT * BTOK + base];
        a4 += partials[(size_t)4 * NSLOT * BTOK + base];
    }
    fsum[w][rl][0] = a0; fsum[w][rl][1] = a1; fsum[w][rl][2] = a2;
    fsum[w][rl][3] = a3; fsum[w][rl][4] = a4;
    __syncthreads();
    if (t < 64) {
        const float es = fsum[0][t][0] + fsum[1][t][0] + fsum[2][t][0] + fsum[3][t][0];
        const float dt = fsum[0][t][1] + fsum[1][t][1] + fsum[2][t][1] + fsum[3][t][1];
        const float ss = fsum[0][t][2] + fsum[1][t][2] + fsum[2][t][2] + fsum[3][t][2];
        const float tt = fsum[0][t][3] + fsum[1][t][3] + fsum[2][t][3] + fsum[3][t][3];
        const float sl = fsum[0][t][4] + fsum[1][t][4] + fsum[2][t][4] + fsum[3][t][4];
        float hard = 0.f, soft;
        if (labels[row] != -100) hard = logf(es) - sl;
        const float ns = fmaxf(sqrtf(ss), 1e-12f);
        const float nt = fmaxf(sqrtf(tt), 1e-12f);
        soft = 1.f - dt / (ns * nt);
#pragma unroll
        for (int m = 1; m < 64; m <<= 1) {
            hard += __shfl_xor(hard, m, 64);
            soft += __shfl_xor(soft, m, 64);
        }
        if (t == 0) {
            blocksums[b * 2 + 0] = hard;
            blocksums[b * 2 + 1] = soft;
        }
    }
}

__global__ void finalize_s2(const float* __restrict__ blocksums,
                            float* __restrict__ out)
{
    const int t = threadIdx.x;   // 64
    float hard = (t < 32) ? blocksums[t * 2 + 0] : 0.f;
    float soft = (t < 32) ? blocksums[t * 2 + 1] : 0.f;
#pragma unroll
    for (int m = 1; m < 64; m <<= 1) {
        hard += __shfl_xor(hard, m, 64);
        soft += __shfl_xor(soft, m, 64);
    }
    if (t == 0)
        out[0] = 0.5f * (hard / (float)BTOK) + 0.25f * (soft / (float)BTOK);
}

// ---------------------------------------------------------------------------
// Fallback (ws too small): R2's validated bf16 fused-conversion kernel.
// ---------------------------------------------------------------------------
#define BKF 32
#define NKTF (HDIM / BKF)
#define TILE_EF (BM * BKF)

__device__ __forceinline__ int swz_e32(int r, int c) {
    return (r * BKF + c) ^ ((r & 7) << 3);
}

__global__ __launch_bounds__(256, 2) void fused_fwd_fb(
    const float* __restrict__ s_in, const float* __restrict__ s_w,
    const float* __restrict__ t_in, const float* __restrict__ t_w,
    const int* __restrict__ labels, float* __restrict__ rowacc)
{
    __shared__ unsigned short smem[2][4][TILE_EF];
    __shared__ int lbl[BM];
    const int tid = threadIdx.x;
    const int orig = blockIdx.x;
    const int swz  = (orig & 7) * (NBLK / 8) + (orig >> 3);
    const int vb = swz >> 4, rb = swz & 15;
    const int n0 = vb * BN, row0 = rb * BM;
    if (tid < BM) lbl[tid] = labels[row0 + tid];
    const int rr = tid >> 3, c8 = tid & 7;
    const float* srcp[4];
    srcp[0] = s_in + (size_t)(row0 + rr) * HDIM + c8 * 4;
    srcp[1] = s_w  + (size_t)(n0   + rr) * HDIM + c8 * 4;
    srcp[2] = t_in + (size_t)(row0 + rr) * HDIM + c8 * 4;
    srcp[3] = t_w  + (size_t)(n0   + rr) * HDIM + c8 * 4;
    f32x4 acc_s[4][4] = {}, acc_t[4][4] = {};
    const int lane = tid & 63, wave = tid >> 6;
    const int wm = (wave >> 1) * 64, wn = (wave & 1) * 64;
    const int lr = lane & 15, lg = lane >> 4;
    const int ec = lg * 8;
    float4 rg[4][4];

#define LOADS_FB(KT)                                                          \
    { const int k0 = (KT) * BKF;                                              \
      _Pragma("unroll") for (int t = 0; t < 4; ++t)                           \
      _Pragma("unroll") for (int it = 0; it < 4; ++it)                        \
          rg[t][it] = *reinterpret_cast<const float4*>(srcp[t] + (size_t)it * 32 * HDIM + k0); }
#define CVT_WRITE_FB(B)                                                       \
    { _Pragma("unroll") for (int t = 0; t < 4; ++t)                           \
      _Pragma("unroll") for (int it = 0; it < 4; ++it) {                      \
          const int r = rr + it * 32;                                         \
          ushort4 h;                                                          \
          h.x = f2b(rg[t][it].x); h.y = f2b(rg[t][it].y);                     \
          h.z = f2b(rg[t][it].z); h.w = f2b(rg[t][it].w);                     \
          *reinterpret_cast<ushort4*>(&smem[B][t][swz_e32(r, c8 * 4)]) = h; } }
#define COMPUTE_FB(B)                                                         \
    { const unsigned short* As = smem[B][0]; const unsigned short* Bs = smem[B][1]; \
      const unsigned short* At = smem[B][2]; const unsigned short* Bt = smem[B][3]; \
      bf16x8 af[4], bfr[4];                                                   \
      _Pragma("unroll") for (int mi = 0; mi < 4; ++mi)                        \
          af[mi] = *reinterpret_cast<const bf16x8*>(As + swz_e32(wm + mi * 16 + lr, ec)); \
      _Pragma("unroll") for (int ni = 0; ni < 4; ++ni)                        \
          bfr[ni] = *reinterpret_cast<const bf16x8*>(Bs + swz_e32(wn + ni * 16 + lr, ec)); \
      _Pragma("unroll") for (int mi = 0; mi < 4; ++mi)                        \
      _Pragma("unroll") for (int ni = 0; ni < 4; ++ni)                        \
          acc_s[mi][ni] = __builtin_amdgcn_mfma_f32_16x16x32_bf16(af[mi], bfr[ni], acc_s[mi][ni], 0, 0, 0); \
      _Pragma("unroll") for (int mi = 0; mi < 4; ++mi)                        \
          af[mi] = *reinterpret_cast<const bf16x8*>(At + swz_e32(wm + mi * 16 + lr, ec)); \
      _Pragma("unroll") for (int ni = 0; ni < 4; ++ni)                        \
          bfr[ni] = *reinterpret_cast<const bf16x8*>(Bt + swz_e32(wn + ni * 16 + lr, ec)); \
      _Pragma("unroll") for (int mi = 0; mi < 4; ++mi)                        \
      _Pragma("unroll") for (int ni = 0; ni < 4; ++ni)                        \
          acc_t[mi][ni] = __builtin_amdgcn_mfma_f32_16x16x32_bf16(af[mi], bfr[ni], acc_t[mi][ni], 0, 0, 0); }

    LOADS_FB(0); CVT_WRITE_FB(0); __syncthreads();
    int cur = 0;
#pragma unroll 2
    for (int kt = 0; kt < NKTF; ++kt) {
        if (kt + 1 < NKTF) LOADS_FB(kt + 1);
        COMPUTE_FB(cur);
        if (kt + 1 < NKTF) CVT_WRITE_FB(cur ^ 1);
        __syncthreads();
        cur ^= 1;
    }
#undef LOADS_FB
#undef CVT_WRITE_FB
#undef COMPUTE_FB
#pragma unroll
    for (int mi = 0; mi < 4; ++mi) {
#pragma unroll
        for (int rg_ = 0; rg_ < 4; ++rg_) {
            const int rloc = wm + mi * 16 + lg * 4 + rg_;
            const int lab = lbl[rloc];
            float es = 0.f, dt = 0.f, ss = 0.f, tt = 0.f, sl = 0.f;
#pragma unroll
            for (int ni = 0; ni < 4; ++ni) {
                const float s = acc_s[mi][ni][rg_];
                const float t = acc_t[mi][ni][rg_];
                es += __expf(s); dt += s * t; ss += s * s; tt += t * t;
                if (n0 + wn + ni * 16 + lr == lab) sl += s;
            }
#pragma unroll
            for (int m = 1; m < 16; m <<= 1) {
                es += __shfl_xor(es, m, 64); dt += __shfl_xor(dt, m, 64);
                ss += __shfl_xor(ss, m, 64); tt += __shfl_xor(tt, m, 64);
                sl += __shfl_xor(sl, m, 64);
            }
            if (lr == 0) {
                float* ra = rowacc + (size_t)(row0 + rloc) * 5;
                atomicAdd(ra + 0, es); atomicAdd(ra + 1, dt); atomicAdd(ra + 2, ss);
                atomicAdd(ra + 3, tt); atomicAdd(ra + 4, sl);
            }
        }
    }
}

__global__ __launch_bounds__(256) void finalize(const float* __restrict__ rowacc,
                                                const int* __restrict__ labels,
                                                float* __restrict__ out)
{
    const int tid = threadIdx.x;
    float hard = 0.f, soft = 0.f;
    for (int r = tid; r < BTOK; r += 256) {
        const float* ra = rowacc + (size_t)r * 5;
        const float es = ra[0], dt = ra[1], ss = ra[2], tt = ra[3], sl = ra[4];
        if (labels[r] != -100) hard += logf(es) - sl;
        const float ns = fmaxf(sqrtf(ss), 1e-12f);
        const float nt = fmaxf(sqrtf(tt), 1e-12f);
        soft += 1.f - dt / (ns * nt);
    }
#pragma unroll
    for (int m = 1; m < 64; m <<= 1) {
        hard += __shfl_xor(hard, m, 64);
        soft += __shfl_xor(soft, m, 64);
    }
    __shared__ float sh[2][4];
    const int w = tid >> 6;
    if ((tid & 63) == 0) { sh[0][w] = hard; sh[1][w] = soft; }
    __syncthreads();
    if (tid == 0) {
        const float h = sh[0][0] + sh[0][1] + sh[0][2] + sh[0][3];
        const float s = sh[1][0] + sh[1][1] + sh[1][2] + sh[1][3];
        out[0] = 0.5f * (h / (float)BTOK) + 0.5f * (0.5f * s / (float)BTOK);
    }
}

extern "C" void kernel_launch(void* const* d_in, const int* in_sizes, int n_in,
                              void* d_out, int out_size, void* d_ws, size_t ws_size,
                              hipStream_t stream)
{
    const float* s_in   = (const float*)d_in[0];
    const float* s_w    = (const float*)d_in[1];
    const float* t_in   = (const float*)d_in[2];
    const float* t_w    = (const float*)d_in[3];
    const int*   labels = (const int*)d_in[4];

    if (ws_size >= WS_NEED) {
        unsigned char* blob = (unsigned char*)d_ws + WS_BLOB_OFF;
        float* partials  = (float*)((char*)d_ws + PART_OFF);
        float* blocksums = (float*)d_ws;
        convert_pack_mx<<<2048, 256, 0, stream>>>(s_in, s_w, t_in, t_w, blob);
        fused_gemm_mx<<<NSTRIP, 512, 0, stream>>>(blob, labels, partials);
        finalize_s1<<<BTOK / 64, 256, 0, stream>>>(partials, labels, blocksums);
        finalize_s2<<<1, 64, 0, stream>>>(blocksums, (float*)d_out);
    } else {
        float* rowacc = (float*)d_ws;
        hipMemsetAsync(rowacc, 0, (size_t)BTOK * 5 * sizeof(float), stream);
        fused_fwd_fb<<<NBLK, 256, 0, stream>>>(s_in, s_w, t_in, t_w, labels, rowacc);
        finalize<<<1, 256, 0, stream>>>(rowacc, labels, (float*)d_out);
    }
}

// Round 17
// 191.859 us; speedup vs baseline: 1.4000x; 1.4000x over previous
//
#include <hip/hip_runtime.h>
#include <stdint.h>

#define BTOK 2048
#define HDIM 512
#define VOC  32000
#define BM 128
#define BN 128
#define BKM 64                   // K per step (MX 32x32x64)
#define NKTM (HDIM / BKM)        // 8 K-steps per vocab block
#define BLOBM (BM * BKM)         // 8192 B per (panel, kt) blob (fp8)
#define NVB (VOC / BN)           // 250
#define NRB (BTOK / BM)          // 16
#define NBLK (NVB * NRB)         // 4000 (fallback grid)
#define VBG 5                    // vocab blocks per strip
#define NVBG (NVB / VBG)         // 50
#define NSTRIP (NVBG * NRB)      // 800 (% 8 == 0)
#define NSLOT (NVBG * 2)         // 100 partial slots

// ws layout:
//   [0, 256)        blocksums
//   [65536, ..)     fp8 blobs: s_in | t_in | s_w | t_w
//   [PART_OFF, ..)  partials[5][NSLOT][BTOK] f32
#define WS_BLOB_OFF 65536
#define INB_B ((size_t)BTOK * HDIM)
#define WB_B  ((size_t)VOC * HDIM)
#define BLOB_BYTES (2 * INB_B + 2 * WB_B)          // 34,865,152
#define PART_OFF (WS_BLOB_OFF + BLOB_BYTES)
#define PART_BYTES ((size_t)5 * NSLOT * BTOK * 4)  // 4,096,000
#define WS_NEED (PART_OFF + PART_BYTES)            // ~39 MB

typedef __attribute__((ext_vector_type(8)))  short bf16x8;
typedef __attribute__((ext_vector_type(4)))  float f32x4;
typedef __attribute__((ext_vector_type(16))) float f32x16;
typedef __attribute__((ext_vector_type(8)))  int   i32x8;

__device__ __forceinline__ unsigned short f2b(float f) {
    union { float f; uint32_t u; } x; x.f = f;
    uint32_t u = x.u;
    u += 0x7fffu + ((u >> 16) & 1u);   // RNE (fallback path)
    return (unsigned short)(u >> 16);
}

// ---------------------------------------------------------------------------
// Pass 1: f32 -> fp8 e4m3 blobs. Piece-interleaved panel layout (HW-verified
// conflict-free in R15: SQ_LDS_BANK_CONFLICT = 0):
//   e = (r>>5)*2048 + ((c&31)>>4)*1024 + ((c>>5)*32 + (r&31))*16 + (c&15)
// Lane l's 32B MFMA operand = two 16B pieces at opBase + l*16 / +1024 ->
// consecutive lanes at 16B stride (the conflict-free ds_read pattern).
// ---------------------------------------------------------------------------
__global__ __launch_bounds__(256) void convert_pack_mx(
    const float* __restrict__ s_in, const float* __restrict__ s_w,
    const float* __restrict__ t_in, const float* __restrict__ t_w,
    unsigned char* __restrict__ blob)
{
    unsigned char* sinb = blob;
    unsigned char* tinb = blob + INB_B;
    unsigned char* swb  = blob + 2 * INB_B;
    unsigned char* twb  = blob + 2 * INB_B + WB_B;
    const int total8 = (2 * BTOK + 2 * VOC) * (HDIM / 8);
    for (int f = blockIdx.x * 256 + threadIdx.x; f < total8; f += gridDim.x * 256) {
        const int row = f >> 6;
        const int c8i = f & 63;
        const float* src; unsigned char* dstb; int lrow;
        if (row < BTOK)                { src = s_in; dstb = sinb; lrow = row; }
        else if (row < BTOK + VOC)     { src = s_w;  dstb = swb;  lrow = row - BTOK; }
        else if (row < 2*BTOK + VOC)   { src = t_in; dstb = tinb; lrow = row - (BTOK + VOC); }
        else                           { src = t_w;  dstb = twb;  lrow = row - (2*BTOK + VOC); }
        const float* sp = src + (size_t)lrow * HDIM + c8i * 8;
        const float4 v0 = *reinterpret_cast<const float4*>(sp);
        const float4 v1 = *reinterpret_cast<const float4*>(sp + 4);
        const int p = lrow >> 7, r = lrow & 127;
        const int ccf = c8i * 8, kt = ccf >> 6, cc = ccf & 63;
        const int e = ((r >> 5) << 11) + (((cc & 31) >> 4) << 10)
                    + ((((cc >> 5) << 5) + (r & 31)) << 4) + (cc & 15);
        uint32_t w0 = 0, w1 = 0;
        w0 = __builtin_amdgcn_cvt_pk_fp8_f32(v0.x, v0.y, w0, false);
        w0 = __builtin_amdgcn_cvt_pk_fp8_f32(v0.z, v0.w, w0, true);
        w1 = __builtin_amdgcn_cvt_pk_fp8_f32(v1.x, v1.y, w1, false);
        w1 = __builtin_amdgcn_cvt_pk_fp8_f32(v1.z, v1.w, w1, true);
        uint2 pk; pk.x = w0; pk.y = w1;
        *reinterpret_cast<uint2*>(dstb + (size_t)(p * NKTM + kt) * BLOBM + e) = pk;
    }
}

__device__ __forceinline__ void gl_lds16(const unsigned char* g, unsigned char* l) {
    __builtin_amdgcn_global_load_lds(
        (__attribute__((address_space(1))) const void*)g,
        (__attribute__((address_space(3))) void*)l, 16, 0, 0);
}

// Read one 32B MFMA operand: two 16B pieces at p and p+1024 (conflict-free).
__device__ __forceinline__ i32x8 ld32pc(const unsigned char* p) {
    const int4 lo = *reinterpret_cast<const int4*>(p);
    const int4 hi = *reinterpret_cast<const int4*>(p + 1024);
    i32x8 v;
    v[0] = lo.x; v[1] = lo.y; v[2] = lo.z; v[3] = lo.w;
    v[4] = hi.x; v[5] = hi.y; v[6] = hi.z; v[7] = hi.w;
    return v;
}

// Stage A(KA) and B(KB) panels into buffer BUF (linear copy; layout is
// pre-arranged in the blob). A indexed mod-8, B linear (KB=8 = next g).
#define STAGE_AB(KA, KB, BUF)                                                 \
    {                                                                         \
        const int off = tid * 16;                                             \
        gl_lds16(g0 + (size_t)(KA) * BLOBM + off, &smem[BUF][0][off]);        \
        gl_lds16(pb1 + (size_t)(KB) * BLOBM + off, &smem[BUF][1][off]);       \
        gl_lds16(g2 + (size_t)(KA) * BLOBM + off, &smem[BUF][2][off]);        \
        gl_lds16(pb3 + (size_t)(KB) * BLOBM + off, &smem[BUF][3][off]);       \
    }

// Per wave: 1 A-frag + 2 B-frags per matrix, 4 mfma_scale (scale=1.0: E8M0 127).
#define COMPUTE_MX(B)                                                         \
    {                                                                         \
        i32x8 fa, fb0, fb1;                                                   \
        fa  = ld32pc(&smem[B][0][aOff]);                                      \
        fb0 = ld32pc(&smem[B][1][b0Off]);                                     \
        fb1 = ld32pc(&smem[B][1][b1Off]);                                     \
        acc_s0 = __builtin_amdgcn_mfma_scale_f32_32x32x64_f8f6f4(             \
            fa, fb0, acc_s0, 0, 0, 0, 127, 0, 127);                           \
        acc_s1 = __builtin_amdgcn_mfma_scale_f32_32x32x64_f8f6f4(             \
            fa, fb1, acc_s1, 0, 0, 0, 127, 0, 127);                           \
        fa  = ld32pc(&smem[B][2][aOff]);                                      \
        fb0 = ld32pc(&smem[B][3][b0Off]);                                     \
        fb1 = ld32pc(&smem[B][3][b1Off]);                                     \
        acc_t0 = __builtin_amdgcn_mfma_scale_f32_32x32x64_f8f6f4(             \
            fa, fb0, acc_t0, 0, 0, 0, 127, 0, 127);                           \
        acc_t1 = __builtin_amdgcn_mfma_scale_f32_32x32x64_f8f6f4(             \
            fa, fb1, acc_t1, 0, 0, 0, 127, 0, 127);                          \
    }

#define CORE(B, VM)                                                           \
    {                                                                         \
        asm volatile("s_waitcnt vmcnt(" #VM ")" ::: "memory");                \
        __builtin_amdgcn_sched_barrier(0);                                    \
        __builtin_amdgcn_s_barrier();                                         \
        COMPUTE_MX(B);                                                        \
        __builtin_amdgcn_s_barrier();                                         \
    }

// ---------------------------------------------------------------------------
// Strip GEMM (MX fp8 32x32x64, 8 waves, VBG=5). R15 configuration — the
// measured optimum of this structure space:
//  - dbuf 64 KB LDS, 2 blocks/CU (cross-block overlap per m114 beats deeper
//    single-block pipelines: R16's ring-4/1-blk-CU regressed 170->230 us);
//  - A+B staged every step (correct; R10's A-reuse was stale), counted
//    vmcnt(4) keeps next step's loads in flight, only final step drains;
//  - conflict-free piece layout (R15: SQ_LDS_BANK_CONFLICT = 0);
//  - register loss partials, ONE reduce+write per block (no atomics).
// Register-pressure rewrites (R8/R11/R14) all spilled: 80 partial VGPRs +
// 64 acc + dual-GEMM operands leave no headroom beyond this shape.
// ---------------------------------------------------------------------------
__global__ __launch_bounds__(512, 2) void fused_gemm_mx(
    const unsigned char* __restrict__ blob,
    const int* __restrict__ labels, float* __restrict__ partials)
{
    __shared__ __align__(16) unsigned char smem[2][4][BLOBM];   // 64 KB
    __shared__ int lbl[BM];
    const unsigned char* sinb = blob;
    const unsigned char* tinb = blob + INB_B;
    const unsigned char* swb  = blob + 2 * INB_B;
    const unsigned char* twb  = blob + 2 * INB_B + WB_B;

    const int tid = threadIdx.x;
    const int orig = blockIdx.x;
    const int swzb = (orig & 7) * (NSTRIP / 8) + (orig >> 3);   // XCD-bijective
    const int vbg = swzb >> 4, rb = swzb & 15;
    const int row0 = rb * BM;
    if (tid < BM) lbl[tid] = labels[row0 + tid];
    __syncthreads();

    const int lane = tid & 63, wave = tid >> 6;
    const int wm = (wave >> 1) * 32;      // 4 M-strips of 32
    const int wn = (wave & 1) * 64;       // 2 N-strips of 64
    const int lrow = lane & 31, khalf = lane >> 5;

    // piece-layout fragment offsets: strip*2048 + lane*16 (piece1 at +1024)
    const int aOff  = ((wm >> 5) << 11) + lane * 16;
    const int b0Off = ((wn >> 5) << 11) + lane * 16;
    const int b1Off = b0Off + 2048;

    const unsigned char* g0 = sinb + (size_t)(rb * NKTM) * BLOBM;
    const unsigned char* g2 = tinb + (size_t)(rb * NKTM) * BLOBM;
    const unsigned char* pb1 = swb + (size_t)(vbg * VBG * NKTM) * BLOBM;
    const unsigned char* pb3 = twb + (size_t)(vbg * VBG * NKTM) * BLOBM;

    // labels for this thread's 16 output rows, hoisted to registers
    int labr[16];
#pragma unroll
    for (int rg = 0; rg < 16; ++rg)
        labr[rg] = lbl[wm + (rg & 3) + 8 * (rg >> 2) + 4 * khalf];

    // strip-accumulated loss partials (statically indexed)
    float pes[16], pdt[16], pss[16], ptt[16], psl[16];
#pragma unroll
    for (int i = 0; i < 16; ++i) {
        pes[i] = 0.f; pdt[i] = 0.f; pss[i] = 0.f; ptt[i] = 0.f; psl[i] = 0.f;
    }

    STAGE_AB(0, 0, 0);                    // prologue: 4 loads in flight

    for (int g = 0; g < VBG; ++g) {
        const int n0 = (vbg * VBG + g) * BN;
        f32x16 acc_s0 = {}, acc_s1 = {}, acc_t0 = {}, acc_t1 = {};

        if (g < VBG - 1) {
#pragma unroll
            for (int kt = 0; kt < NKTM - 1; ++kt) {
                STAGE_AB(kt + 1, kt + 1, (kt + 1) & 1);
                CORE(kt & 1, 4);
            }
            STAGE_AB(0, NKTM, 0);         // next g: A(0), B(next block's 0)
            CORE(1, 4);
        } else {
#pragma unroll
            for (int kt = 0; kt < NKTM - 1; ++kt) {
                STAGE_AB(kt + 1, kt + 1, (kt + 1) & 1);
                CORE(kt & 1, 4);
            }
            CORE(1, 0);                   // only full drain in the kernel
        }
        pb1 += (size_t)NKTM * BLOBM;
        pb3 += (size_t)NKTM * BLOBM;

        // accumulate into register partials
        // C/D (32x32): col = lane&31, row = (reg&3)+8*(reg>>2)+4*(lane>>5)
#pragma unroll
        for (int rg = 0; rg < 16; ++rg) {
            const float s0 = acc_s0[rg], s1 = acc_s1[rg];
            const float t0 = acc_t0[rg], t1 = acc_t1[rg];
            pes[rg] += __expf(s0) + __expf(s1);
            pdt[rg] += s0 * t0 + s1 * t1;
            pss[rg] += s0 * s0 + s1 * s1;
            ptt[rg] += t0 * t0 + t1 * t1;
            const int lab = labr[rg];
            if (n0 + wn + lrow == lab)      psl[rg] += s0;
            if (n0 + wn + 32 + lrow == lab) psl[rg] += s1;
        }
    }

    // one shuffle-reduce + one non-atomic write per rg for the whole strip
    const int slot = vbg * 2 + (wave & 1);
#pragma unroll
    for (int rg = 0; rg < 16; ++rg) {
        float es = pes[rg], dt = pdt[rg], ss = pss[rg], tt = ptt[rg], sl = psl[rg];
#pragma unroll
        for (int m = 1; m < 32; m <<= 1) {
            es += __shfl_xor(es, m, 64);
            dt += __shfl_xor(dt, m, 64);
            ss += __shfl_xor(ss, m, 64);
            tt += __shfl_xor(tt, m, 64);
            sl += __shfl_xor(sl, m, 64);
        }
        if (lrow == 0) {
            const int row = row0 + wm + (rg & 3) + 8 * (rg >> 2) + 4 * khalf;
            partials[(size_t)(0 * NSLOT + slot) * BTOK + row] = es;
            partials[(size_t)(1 * NSLOT + slot) * BTOK + row] = dt;
            partials[(size_t)(2 * NSLOT + slot) * BTOK + row] = ss;
            partials[(size_t)(3 * NSLOT + slot) * BTOK + row] = tt;
            partials[(size_t)(4 * NSLOT + slot) * BTOK + row] = sl;
        }
    }
}

// ---------------------------------------------------------------------------
// finalize stage 1: 32 blocks x 64 rows; reduce 100 slots (coalesced).
// ---------------------------------------------------------------------------
__global__ __launch_bounds__(256) void finalize_s1(
    const float* __restrict__ partials, const int* __restrict__ labels,
    float* __restrict__ blocksums)
{
    __shared__ float fsum[4][64][5];
    const int t = threadIdx.x, b = blockIdx.x;
    const int rl = t & 63, w = t >> 6;
    const int row = b * 64 + rl;
    float a0 = 0.f, a1 = 0.f, a2 = 0.f, a3 = 0.f, a4 = 0.f;
    for (int slot = w; slot < NSLOT; slot += 4) {
        const size_t base = (size_t)slot * BTOK + row;
        a0 += partials[(size_t)0 * NSLOT * BTOK + base];
        a1 += partials[(size_t)1 * NSLOT * BTOK + base];
        a2 += partials[(size_t)2 * NSLOT * BTOK + base];
        a3 += partials[(size_t)3 * NSLOT * BTOK + base];
        a4 += partials[(size_t)4 * NSLOT * BTOK + base];
    }
    fsum[w][rl][0] = a0; fsum[w][rl][1] = a1; fsum[w][rl][2] = a2;
    fsum[w][rl][3] = a3; fsum[w][rl][4] = a4;
    __syncthreads();
    if (t < 64) {
        const float es = fsum[0][t][0] + fsum[1][t][0] + fsum[2][t][0] + fsum[3][t][0];
        const float dt = fsum[0][t][1] + fsum[1][t][1] + fsum[2][t][1] + fsum[3][t][1];
        const float ss = fsum[0][t][2] + fsum[1][t][2] + fsum[2][t][2] + fsum[3][t][2];
        const float tt = fsum[0][t][3] + fsum[1][t][3] + fsum[2][t][3] + fsum[3][t][3];
        const float sl = fsum[0][t][4] + fsum[1][t][4] + fsum[2][t][4] + fsum[3][t][4];
        float hard = 0.f, soft;
        if (labels[row] != -100) hard = logf(es) - sl;
        const float ns = fmaxf(sqrtf(ss), 1e-12f);
        const float nt = fmaxf(sqrtf(tt), 1e-12f);
        soft = 1.f - dt / (ns * nt);
#pragma unroll
        for (int m = 1; m < 64; m <<= 1) {
            hard += __shfl_xor(hard, m, 64);
            soft += __shfl_xor(soft, m, 64);
        }
        if (t == 0) {
            blocksums[b * 2 + 0] = hard;
            blocksums[b * 2 + 1] = soft;
        }
    }
}

__global__ void finalize_s2(const float* __restrict__ blocksums,
                            float* __restrict__ out)
{
    const int t = threadIdx.x;   // 64
    float hard = (t < 32) ? blocksums[t * 2 + 0] : 0.f;
    float soft = (t < 32) ? blocksums[t * 2 + 1] : 0.f;
#pragma unroll
    for (int m = 1; m < 64; m <<= 1) {
        hard += __shfl_xor(hard, m, 64);
        soft += __shfl_xor(soft, m, 64);
    }
    if (t == 0)
        out[0] = 0.5f * (hard / (float)BTOK) + 0.25f * (soft / (float)BTOK);
}

// ---------------------------------------------------------------------------
// Fallback (ws too small): R2's validated bf16 fused-conversion kernel.
// ---------------------------------------------------------------------------
#define BKF 32
#define NKTF (HDIM / BKF)
#define TILE_EF (BM * BKF)

__device__ __forceinline__ int swz_e32(int r, int c) {
    return (r * BKF + c) ^ ((r & 7) << 3);
}

__global__ __launch_bounds__(256, 2) void fused_fwd_fb(
    const float* __restrict__ s_in, const float* __restrict__ s_w,
    const float* __restrict__ t_in, const float* __restrict__ t_w,
    const int* __restrict__ labels, float* __restrict__ rowacc)
{
    __shared__ unsigned short smem[2][4][TILE_EF];
    __shared__ int lbl[BM];
    const int tid = threadIdx.x;
    const int orig = blockIdx.x;
    const int swz  = (orig & 7) * (NBLK / 8) + (orig >> 3);
    const int vb = swz >> 4, rb = swz & 15;
    const int n0 = vb * BN, row0 = rb * BM;
    if (tid < BM) lbl[tid] = labels[row0 + tid];
    const int rr = tid >> 3, c8 = tid & 7;
    const float* srcp[4];
    srcp[0] = s_in + (size_t)(row0 + rr) * HDIM + c8 * 4;
    srcp[1] = s_w  + (size_t)(n0   + rr) * HDIM + c8 * 4;
    srcp[2] = t_in + (size_t)(row0 + rr) * HDIM + c8 * 4;
    srcp[3] = t_w  + (size_t)(n0   + rr) * HDIM + c8 * 4;
    f32x4 acc_s[4][4] = {}, acc_t[4][4] = {};
    const int lane = tid & 63, wave = tid >> 6;
    const int wm = (wave >> 1) * 64, wn = (wave & 1) * 64;
    const int lr = lane & 15, lg = lane >> 4;
    const int ec = lg * 8;
    float4 rg[4][4];

#define LOADS_FB(KT)                                                          \
    { const int k0 = (KT) * BKF;                                              \
      _Pragma("unroll") for (int t = 0; t < 4; ++t)                           \
      _Pragma("unroll") for (int it = 0; it < 4; ++it)                        \
          rg[t][it] = *reinterpret_cast<const float4*>(srcp[t] + (size_t)it * 32 * HDIM + k0); }
#define CVT_WRITE_FB(B)                                                       \
    { _Pragma("unroll") for (int t = 0; t < 4; ++t)                           \
      _Pragma("unroll") for (int it = 0; it < 4; ++it) {                      \
          const int r = rr + it * 32;                                         \
          ushort4 h;                                                          \
          h.x = f2b(rg[t][it].x); h.y = f2b(rg[t][it].y);                     \
          h.z = f2b(rg[t][it].z); h.w = f2b(rg[t][it].w);                     \
          *reinterpret_cast<ushort4*>(&smem[B][t][swz_e32(r, c8 * 4)]) = h; } }
#define COMPUTE_FB(B)                                                         \
    { const unsigned short* As = smem[B][0]; const unsigned short* Bs = smem[B][1]; \
      const unsigned short* At = smem[B][2]; const unsigned short* Bt = smem[B][3]; \
      bf16x8 af[4], bfr[4];                                                   \
      _Pragma("unroll") for (int mi = 0; mi < 4; ++mi)                        \
          af[mi] = *reinterpret_cast<const bf16x8*>(As + swz_e32(wm + mi * 16 + lr, ec)); \
      _Pragma("unroll") for (int ni = 0; ni < 4; ++ni)                        \
          bfr[ni] = *reinterpret_cast<const bf16x8*>(Bs + swz_e32(wn + ni * 16 + lr, ec)); \
      _Pragma("unroll") for (int mi = 0; mi < 4; ++mi)                        \
      _Pragma("unroll") for (int ni = 0; ni < 4; ++ni)                        \
          acc_s[mi][ni] = __builtin_amdgcn_mfma_f32_16x16x32_bf16(af[mi], bfr[ni], acc_s[mi][ni], 0, 0, 0); \
      _Pragma("unroll") for (int mi = 0; mi < 4; ++mi)                        \
          af[mi] = *reinterpret_cast<const bf16x8*>(At + swz_e32(wm + mi * 16 + lr, ec)); \
      _Pragma("unroll") for (int ni = 0; ni < 4; ++ni)                        \
          bfr[ni] = *reinterpret_cast<const bf16x8*>(Bt + swz_e32(wn + ni * 16 + lr, ec)); \
      _Pragma("unroll") for (int mi = 0; mi < 4; ++mi)                        \
      _Pragma("unroll") for (int ni = 0; ni < 4; ++ni)                        \
          acc_t[mi][ni] = __builtin_amdgcn_mfma_f32_16x16x32_bf16(af[mi], bfr[ni], acc_t[mi][ni], 0, 0, 0); }

    LOADS_FB(0); CVT_WRITE_FB(0); __syncthreads();
    int cur = 0;
#pragma unroll 2
    for (int kt = 0; kt < NKTF; ++kt) {
        if (kt + 1 < NKTF) LOADS_FB(kt + 1);
        COMPUTE_FB(cur);
        if (kt + 1 < NKTF) CVT_WRITE_FB(cur ^ 1);
        __syncthreads();
        cur ^= 1;
    }
#undef LOADS_FB
#undef CVT_WRITE_FB
#undef COMPUTE_FB
#pragma unroll
    for (int mi = 0; mi < 4; ++mi) {
#pragma unroll
        for (int rg_ = 0; rg_ < 4; ++rg_) {
            const int rloc = wm + mi * 16 + lg * 4 + rg_;
            const int lab = lbl[rloc];
            float es = 0.f, dt = 0.f, ss = 0.f, tt = 0.f, sl = 0.f;
#pragma unroll
            for (int ni = 0; ni < 4; ++ni) {
                const float s = acc_s[mi][ni][rg_];
                const float t = acc_t[mi][ni][rg_];
                es += __expf(s); dt += s * t; ss += s * s; tt += t * t;
                if (n0 + wn + ni * 16 + lr == lab) sl += s;
            }
#pragma unroll
            for (int m = 1; m < 16; m <<= 1) {
                es += __shfl_xor(es, m, 64); dt += __shfl_xor(dt, m, 64);
                ss += __shfl_xor(ss, m, 64); tt += __shfl_xor(tt, m, 64);
                sl += __shfl_xor(sl, m, 64);
            }
            if (lr == 0) {
                float* ra = rowacc + (size_t)(row0 + rloc) * 5;
                atomicAdd(ra + 0, es); atomicAdd(ra + 1, dt); atomicAdd(ra + 2, ss);
                atomicAdd(ra + 3, tt); atomicAdd(ra + 4, sl);
            }
        }
    }
}

__global__ __launch_bounds__(256) void finalize(const float* __restrict__ rowacc,
                                                const int* __restrict__ labels,
                                                float* __restrict__ out)
{
    const int tid = threadIdx.x;
    float hard = 0.f, soft = 0.f;
    for (int r = tid; r < BTOK; r += 256) {
        const float* ra = rowacc + (size_t)r * 5;
        const float es = ra[0], dt = ra[1], ss = ra[2], tt = ra[3], sl = ra[4];
        if (labels[r] != -100) hard += logf(es) - sl;
        const float ns = fmaxf(sqrtf(ss), 1e-12f);
        const float nt = fmaxf(sqrtf(tt), 1e-12f);
        soft += 1.f - dt / (ns * nt);
    }
#pragma unroll
    for (int m = 1; m < 64; m <<= 1) {
        hard += __shfl_xor(hard, m, 64);
        soft += __shfl_xor(soft, m, 64);
    }
    __shared__ float sh[2][4];
    const int w = tid >> 6;
    if ((tid & 63) == 0) { sh[0][w] = hard; sh[1][w] = soft; }
    __syncthreads();
    if (tid == 0) {
        const float h = sh[0][0] + sh[0][1] + sh[0][2] + sh[0][3];
        const float s = sh[1][0] + sh[1][1] + sh[1][2] + sh[1][3];
        out[0] = 0.5f * (h / (float)BTOK) + 0.5f * (0.5f * s / (float)BTOK);
    }
}

extern "C" void kernel_launch(void* const* d_in, const int* in_sizes, int n_in,
                              void* d_out, int out_size, void* d_ws, size_t ws_size,
                              hipStream_t stream)
{
    const float* s_in   = (const float*)d_in[0];
    const float* s_w    = (const float*)d_in[1];
    const float* t_in   = (const float*)d_in[2];
    const float* t_w    = (const float*)d_in[3];
    const int*   labels = (const int*)d_in[4];

    if (ws_size >= WS_NEED) {
        unsigned char* blob = (unsigned char*)d_ws + WS_BLOB_OFF;
        float* partials  = (float*)((char*)d_ws + PART_OFF);
        float* blocksums = (float*)d_ws;
        convert_pack_mx<<<2048, 256, 0, stream>>>(s_in, s_w, t_in, t_w, blob);
        fused_gemm_mx<<<NSTRIP, 512, 0, stream>>>(blob, labels, partials);
        finalize_s1<<<BTOK / 64, 256, 0, stream>>>(partials, labels, blocksums);
        finalize_s2<<<1, 64, 0, stream>>>(blocksums, (float*)d_out);
    } else {
        float* rowacc = (float*)d_ws;
        hipMemsetAsync(rowacc, 0, (size_t)BTOK * 5 * sizeof(float), stream);
        fused_fwd_fb<<<NBLK, 256, 0, stream>>>(s_in, s_w, t_in, t_w, labels, rowacc);
        finalize<<<1, 256, 0, stream>>>(rowacc, labels, (float*)d_out);
    }
}